// Round 10
// baseline (938.313 us; speedup 1.0000x reference)
//
#include <hip/hip_runtime.h>
#include <stdint.h>

#define T_ 512
#define B_ 32
#define V_ 512
#define L_ 128
#define NEGF (-1000000000.0f)

// Signed-i8 quantization: E = exp(trans) in ~[0.55,1.83]; SE*1.83 < 127.
#define SE_Q 69.0f
#define SU_Q 127.0f
#define LOGC 9.078313f   /* log(SE_Q * SU_Q) */

typedef int v4i __attribute__((ext_vector_type(4)));

// ---- DPP helpers (VALU pipe) ----------------------------------------------
template <int CTRL>
__device__ __forceinline__ int dppmov(int old_, int src) {
    return __builtin_amdgcn_update_dpp(old_, src, CTRL, 0xF, 0xF, false);
}
__device__ __forceinline__ float wave_max64(float x) {
    int xi = __float_as_int(x);
    x = fmaxf(x, __int_as_float(dppmov<0x111>(xi, xi))); xi = __float_as_int(x);
    x = fmaxf(x, __int_as_float(dppmov<0x112>(xi, xi))); xi = __float_as_int(x);
    x = fmaxf(x, __int_as_float(dppmov<0x114>(xi, xi))); xi = __float_as_int(x);
    x = fmaxf(x, __int_as_float(dppmov<0x118>(xi, xi))); xi = __float_as_int(x);
    x = fmaxf(x, __int_as_float(dppmov<0x142>(xi, xi))); xi = __float_as_int(x);
    x = fmaxf(x, __int_as_float(dppmov<0x143>(xi, xi)));
    return x;   // fully reduced in lane 63
}
__device__ __forceinline__ float wave_sum64(float x) {
    int xi = __float_as_int(x);
    x = x + __int_as_float(dppmov<0x111>(xi, xi)); xi = __float_as_int(x);
    x = x + __int_as_float(dppmov<0x112>(xi, xi)); xi = __float_as_int(x);
    x = x + __int_as_float(dppmov<0x114>(xi, xi)); xi = __float_as_int(x);
    x = x + __int_as_float(dppmov<0x118>(xi, xi)); xi = __float_as_int(x);
    x = x + __int_as_float(dppmov<0x142>(xi, xi)); xi = __float_as_int(x);
    x = x + __int_as_float(dppmov<0x143>(xi, xi));
    return x;
}
// monotonic float<->uint for LDS atomicMax (epilogue only)
__device__ __forceinline__ unsigned fkey(float f) {
    unsigned u = __float_as_uint(f);
    return (u & 0x80000000u) ? ~u : (u | 0x80000000u);
}
__device__ __forceinline__ float funkey(unsigned k) {
    unsigned u = (k & 0x80000000u) ? (k ^ 0x80000000u) : ~k;
    return __uint_as_float(u);
}
// select element r (0..3) of a v4i — 3 cndmask, no scratch
__device__ __forceinline__ int sel4(v4i a, int r) {
    int x0 = (r & 1) ? a.y : a.x;
    int x1 = (r & 1) ? a.w : a.z;
    return (r & 2) ? x1 : x0;
}

// ---------------- prep: quantize E into MFMA A-fragment layout --------------
// (unchanged R2 layout; asg_main's er4 load is identical)
__global__ void asg_prep(const float* __restrict__ trans, uint32_t* __restrict__ Et) {
    int o = blockIdx.x * blockDim.x + threadIdx.x;      // 0 .. 65535
    int d    = o & 3;
    int tid  = (o >> 2) & 511;
    int qreg = o >> 11;                                  // 0..31
    int tt = qreg >> 3, kt = qreg & 7;
    int w = tid >> 6, lane = tid & 63;
    int q = lane >> 4, n = lane & 15;
    int m  = 64 * w + 16 * tt + n;
    int k0 = 64 * kt + 16 * q + 4 * d;
    const float* tp = trans + (size_t)m * V_ + k0;
    uint32_t q0 = (uint32_t)fminf(127.0f, __expf(tp[0]) * SE_Q + 0.5f);
    uint32_t q1 = (uint32_t)fminf(127.0f, __expf(tp[1]) * SE_Q + 0.5f);
    uint32_t q2 = (uint32_t)fminf(127.0f, __expf(tp[2]) * SE_Q + 0.5f);
    uint32_t q3 = (uint32_t)fminf(127.0f, __expf(tp[3]) * SE_Q + 0.5f);
    Et[(size_t)o] = q0 | (q1 << 8) | (q2 << 16) | (q3 << 24);
}

// ---------------- fused main: blocks 0..15 = FCC pair, 16..47 = FAC ---------
// FCC dual-batch: block bb runs batches bA=2bb, bB=2bb+1. E (er4, AGPR) is
// SHARED; only the tiny scalar DP state and u_lds duplicate. Per double-step
// the two barriers, LDS round-trips and DPP chains are paid ONCE:
//   phase1: waveMax A, waveMax B (independent DPP chains interleave)
//           -> mwA[w], mwB[w] -> barrier 1
//   phase2: kmax A/B (broadcast reads + fmax trees) -> quant/pack A -> uA;
//           quant/pack B -> uB -> barrier 2
//   phase3: bfA reads -> MFMA A x32 (4 AGPR chains) -> sel A -> bfB reads
//           (same registers, latency hidden under MFMA A) -> MFMA B x32
//           (shared accumulators, extracted A first) -> sel B -> state updates.
// Numerics per batch = R4 exactly (global max + implicit alpha, absmax 0.0).
__global__ __attribute__((amdgpu_flat_work_group_size(512, 512),
                          amdgpu_waves_per_eu(2, 2)))
void asg_main(
    const float* __restrict__ lp, const uint32_t* __restrict__ Et,
    const float* __restrict__ trans, const int* __restrict__ targets,
    const int* __restrict__ ilen, const int* __restrict__ tlen,
    float* __restrict__ fcc_ws, float* __restrict__ fac_ws)
{
    __shared__ float facb[256];                       // fac double buffer
    __shared__ __align__(16) uint32_t uA_lds[128];    // u8[512], batch A
    __shared__ __align__(16) uint32_t uB_lds[128];    // u8[512], batch B
    __shared__ __align__(16) float mwA[8];            // per-wave key maxes A
    __shared__ __align__(16) float mwB[8];            // per-wave key maxes B
    __shared__ unsigned mslotA, mslotB;
    __shared__ float sumfA, sumfB;

    const int bb  = blockIdx.x;
    const int tid = threadIdx.x;

    if (bb < B_ / 2) {
        // ================= FCC pair =======================================
        const int bA   = 2 * bb;
        const int bB   = 2 * bb + 1;
        const int lane = tid & 63;
        const int w    = tid >> 6;              // wave 0..7, rows 64w..64w+63
        const int q    = lane >> 4;             // 0..3
        const int n    = lane & 15;             // 0..15
        const int tt_o = n >> 2;                // owned tile
        const int rg_o = n & 3;                 // owned reg (row-in-4)
        const int i    = 64 * w + 16 * tt_o + 4 * q + rg_o;   // owned row
        const int TlenA = ilen[bA];
        const int TlenB = ilen[bB];
        const int Tmax  = (TlenA > TlenB) ? TlenA : TlenB;

        // er: 32 uint4 A-frags, shared by both batches (dumb loads -> AGPR)
        uint4 er4[32];
        {
            const uint4* Eq = (const uint4*)Et;
            #pragma unroll
            for (int t8 = 0; t8 < 32; ++t8) er4[t8] = Eq[t8 * 512 + tid];
        }

        // ---- implicit-alpha state per batch: alpha = lpv + S + log(accf)
        float lpv0A = lp[(size_t)bA * V_ + i];
        float lpv0B = lp[(size_t)bB * V_ + i];
        float elpA = __expf(lpv0A), elpB = __expf(lpv0B);
        float lpvA = lp[(size_t)(B_ * V_) + (size_t)bA * V_ + i];
        float lpvB = lp[(size_t)(B_ * V_) + (size_t)bB * V_ + i];
        float accfA = 1.0f, accfB = 1.0f;
        float SA = 0.0f, SB = 0.0f;
        if (tid == 0) { mslotA = 0u; mslotB = 0u; sumfA = 0.0f; sumfB = 0.0f; }
        __syncthreads();

        for (int t = 1; t < Tmax; ++t) {
            // ---- phase 1: wave maxes (independent chains interleave)
            float keyA = elpA * accfA;
            float keyB = elpB * accfB;
            float mxA = wave_max64(keyA);
            float mxB = wave_max64(keyB);
            if (lane == 63) { mwA[w] = mxA; mwB[w] = mxB; }
            __syncthreads();                           // [mw visible]

            // ---- phase 2: global maxes + quantize both batches
            float4 a0 = *(const float4*)&mwA[0];
            float4 a1 = *(const float4*)&mwA[4];
            float4 b0 = *(const float4*)&mwB[0];
            float4 b1 = *(const float4*)&mwB[4];
            float kmA = fmaxf(fmaxf(fmaxf(a0.x, a0.y), fmaxf(a0.z, a0.w)),
                              fmaxf(fmaxf(a1.x, a1.y), fmaxf(a1.z, a1.w)));
            float kmB = fmaxf(fmaxf(fmaxf(b0.x, b0.y), fmaxf(b0.z, b0.w)),
                              fmaxf(fmaxf(b1.x, b1.y), fmaxf(b1.z, b1.w)));
            float rA = 127.0f * __builtin_amdgcn_rcpf(kmA);
            float rB = 127.0f * __builtin_amdgcn_rcpf(kmB);
            {
                uint32_t qu = (uint32_t)fminf(127.0f, fmaf(keyA, rA, 0.5f));
                int pv = (int)(qu << (8 * (i & 3)));
                pv |= dppmov<0xB1>(pv, pv);
                pv |= dppmov<0x4E>(pv, pv);
                if ((i & 3) == 0) uA_lds[i >> 2] = (uint32_t)pv;
            }
            {
                uint32_t qu = (uint32_t)fminf(127.0f, fmaf(keyB, rB, 0.5f));
                int pv = (int)(qu << (8 * (i & 3)));
                pv |= dppmov<0xB1>(pv, pv);
                pv |= dppmov<0x4E>(pv, pv);
                if ((i & 3) == 0) uB_lds[i >> 2] = (uint32_t)pv;
            }
            __syncthreads();                           // [u visible]

            // ---- phase 3a: batch A MFMA
            uint4 bfA[8];
            #pragma unroll
            for (int kt = 0; kt < 8; ++kt)
                bfA[kt] = *(const uint4*)((const char*)uA_lds + 64 * kt + 16 * q);

            int tnA = (t + 1 < TlenA) ? (t + 1) : (TlenA - 1);
            float lpvA_n = lp[(size_t)tnA * (B_ * V_) + (size_t)bA * V_ + i];
            float elpA_n = __expf(lpvA);               // off critical path

            v4i c0, c1, c2, c3;
            {
                v4i z = {0, 0, 0, 0};
                c0 = z; c1 = z; c2 = z; c3 = z;
            }
            #pragma unroll
            for (int kt = 0; kt < 8; ++kt) {
                v4i bv = __builtin_bit_cast(v4i, bfA[kt]);
                c0 = __builtin_amdgcn_mfma_i32_16x16x64_i8(
                        __builtin_bit_cast(v4i, er4[0 * 8 + kt]), bv, c0, 0, 0, 0);
                c1 = __builtin_amdgcn_mfma_i32_16x16x64_i8(
                        __builtin_bit_cast(v4i, er4[1 * 8 + kt]), bv, c1, 0, 0, 0);
                c2 = __builtin_amdgcn_mfma_i32_16x16x64_i8(
                        __builtin_bit_cast(v4i, er4[2 * 8 + kt]), bv, c2, 0, 0, 0);
                c3 = __builtin_amdgcn_mfma_i32_16x16x64_i8(
                        __builtin_bit_cast(v4i, er4[3 * 8 + kt]), bv, c3, 0, 0, 0);
            }
            int accA;
            {
                int s0 = sel4(c0, rg_o), s1 = sel4(c1, rg_o);
                int s2 = sel4(c2, rg_o), s3 = sel4(c3, rg_o);
                int y0 = (tt_o & 1) ? s1 : s0;
                int y1 = (tt_o & 1) ? s3 : s2;
                accA = (tt_o & 2) ? y1 : y0;
            }

            // ---- phase 3b: batch B MFMA (B-frag reads + exp hidden under A)
            uint4 bfB[8];
            #pragma unroll
            for (int kt = 0; kt < 8; ++kt)
                bfB[kt] = *(const uint4*)((const char*)uB_lds + 64 * kt + 16 * q);

            int tnB = (t + 1 < TlenB) ? (t + 1) : (TlenB - 1);
            float lpvB_n = lp[(size_t)tnB * (B_ * V_) + (size_t)bB * V_ + i];
            float elpB_n = __expf(lpvB);

            {
                v4i z = {0, 0, 0, 0};
                c0 = z; c1 = z; c2 = z; c3 = z;
            }
            #pragma unroll
            for (int kt = 0; kt < 8; ++kt) {
                v4i bv = __builtin_bit_cast(v4i, bfB[kt]);
                c0 = __builtin_amdgcn_mfma_i32_16x16x64_i8(
                        __builtin_bit_cast(v4i, er4[0 * 8 + kt]), bv, c0, 0, 0, 0);
                c1 = __builtin_amdgcn_mfma_i32_16x16x64_i8(
                        __builtin_bit_cast(v4i, er4[1 * 8 + kt]), bv, c1, 0, 0, 0);
                c2 = __builtin_amdgcn_mfma_i32_16x16x64_i8(
                        __builtin_bit_cast(v4i, er4[2 * 8 + kt]), bv, c2, 0, 0, 0);
                c3 = __builtin_amdgcn_mfma_i32_16x16x64_i8(
                        __builtin_bit_cast(v4i, er4[3 * 8 + kt]), bv, c3, 0, 0, 0);
            }
            int accB;
            {
                int s0 = sel4(c0, rg_o), s1 = sel4(c1, rg_o);
                int s2 = sel4(c2, rg_o), s3 = sel4(c3, rg_o);
                int y0 = (tt_o & 1) ? s1 : s0;
                int y1 = (tt_o & 1) ? s3 : s2;
                accB = (tt_o & 2) ? y1 : y0;
            }

            // ---- state updates (guarded; uniform branches)
            if (t < TlenA) {
                accfA = (float)accA;
                SA += __logf(kmA) - LOGC;
                elpA = elpA_n;
                lpvA = lpvA_n;
            }
            if (t < TlenB) {
                accfB = (float)accB;
                SB += __logf(kmB) - LOGC;
                elpB = elpB_n;
                lpvB = lpvB_n;
            }
        }

        // ---- epilogues: reconstruct alphas, exact f32 logsumexp per batch
        float alphaA = ((TlenA > 1) ? lpvA : lpv0A) + SA + __logf(accfA);
        float alphaB = ((TlenB > 1) ? lpvB : lpv0B) + SB + __logf(accfB);
        {
            float mA = wave_max64(alphaA);
            float mB = wave_max64(alphaB);
            if (lane == 63) {
                atomicMax(&mslotA, fkey(mA));
                atomicMax(&mslotB, fkey(mB));
            }
        }
        __syncthreads();
        float m2A = funkey(mslotA);
        float m2B = funkey(mslotB);
        {
            float svA = wave_sum64(__expf(alphaA - m2A));
            float svB = wave_sum64(__expf(alphaB - m2B));
            if (lane == 63) {
                atomicAdd(&sumfA, svA);
                atomicAdd(&sumfB, svB);
            }
        }
        __syncthreads();
        if (tid == 0) {
            fcc_ws[bA] = m2A + __logf(sumfA);
            fcc_ws[bB] = m2B + __logf(sumfB);
        }
    } else {
        // ================= FAC (threads 0..127 active) =====================
        const int b = bb - B_ / 2;
        const int l = tid;
        const bool active = (l < L_);
        const int Tlen = ilen[b];
        const int Llen = tlen[b];

        const int tl  = active ? targets[b * L_ + l] : 0;
        const int tlm = (active && l > 0) ? targets[b * L_ + l - 1] : 0;
        const float ts = active ? trans[(size_t)tl * V_ + tl] : 0.0f;
        const float tp = (active && l > 0) ? trans[(size_t)tl * V_ + tlm] : 0.0f;

        float beta = (l == 0) ? lp[(size_t)b * V_ + tl] : NEGF;
        float em_next = active ? lp[(size_t)1 * (B_ * V_) + (size_t)b * V_ + tl] : 0.0f;

        for (int t = 1; t < Tlen; ++t) {
            float* buf = facb + (t & 1) * L_;
            if (active) buf[l] = beta;
            __syncthreads();
            float prev = (active && l > 0) ? buf[l - 1] : NEGF;
            float em = em_next;
            if (active && t + 1 < Tlen)
                em_next = lp[(size_t)(t + 1) * (B_ * V_) + (size_t)b * V_ + tl];
            if (active) {
                float st = beta + ts;
                float mv = prev + tp;
                float mx = fmaxf(st, mv);
                float mn = fminf(st, mv);
                beta = em + mx + log1pf(__expf(mn - mx));
            }
        }
        if (active && l == Llen - 1) fac_ws[b] = beta;
    }
}

// ---------------- combine ---------------------------------------------------
__global__ void asg_combine(const float* __restrict__ fcc_ws,
                            const float* __restrict__ fac_ws,
                            float* __restrict__ out) {
    int i = threadIdx.x;
    if (i < B_) out[i] = fcc_ws[i] - fac_ws[i];
}

extern "C" void kernel_launch(void* const* d_in, const int* in_sizes, int n_in,
                              void* d_out, int out_size, void* d_ws, size_t ws_size,
                              hipStream_t stream) {
    const float* lp      = (const float*)d_in[0];
    const float* trans   = (const float*)d_in[1];
    const int*   targets = (const int*)d_in[2];
    const int*   ilen    = (const int*)d_in[3];
    const int*   tlen    = (const int*)d_in[4];
    float* out = (float*)d_out;

    uint32_t* Et     = (uint32_t*)d_ws;                    // 65536 dwords = 256 KB
    float*    fcc_ws = (float*)((char*)d_ws + 65536 * 4);
    float*    fac_ws = fcc_ws + B_;

    hipLaunchKernelGGL(asg_prep, dim3(256), dim3(256), 0, stream, trans, Et);
    hipLaunchKernelGGL(asg_main, dim3(B_ / 2 + B_), dim3(512), 0, stream,
                       lp, Et, trans, targets, ilen, tlen, fcc_ws, fac_ws);
    hipLaunchKernelGGL(asg_combine, dim3(1), dim3(64), 0, stream, fcc_ws, fac_ws, out);
}